// Round 7
// baseline (9055.289 us; speedup 1.0000x reference)
//
#include <hip/hip_runtime.h>
#include <stdint.h>

#define T_STEPS 2048
#define BATCH   64
#define IN_SZ   256
#define HID     512
#define FANG    768          // HID + IN_SZ
#define NLAYER  2
#define TOT_STEPS (T_STEPS*NLAYER)

typedef _Float16 h2 __attribute__((ext_vector_type(2)));
typedef unsigned long long u64;
typedef unsigned int u32;

__device__ __forceinline__ float dot2f(h2 a, h2 b, float c) {
#if __has_builtin(__builtin_amdgcn_fdot2)
    return __builtin_amdgcn_fdot2(a, b, c, false);
#else
    return c + (float)a.x * (float)b.x + (float)a.y * (float)b.y;
#endif
}

__device__ __forceinline__ u32 packh2(float a, float b) {
    h2 t{(_Float16)a, (_Float16)b};
    return __builtin_bit_cast(u32, t);
}
__device__ __forceinline__ h2 bch2(float v) { return __builtin_bit_cast(h2, v); }

// DPP quad reduce: after xor1 (0xB1) + xor2 (0x4E) every lane of a quad
// holds the 4-lane sum. CTRL must be compile-time constant.
template<int CTRL>
__device__ __forceinline__ float dpp_add(float x) {
    int xi = __builtin_bit_cast(int, x);
    int yi = __builtin_amdgcn_update_dpp(0, xi, CTRL, 0xf, 0xf, true);
    return x + __builtin_bit_cast(float, yi);
}
__device__ __forceinline__ float reduce4(float x) {
    x = dpp_add<0xB1>(x);
    x = dpp_add<0x4E>(x);
    return x;
}

// -------------------------------------------------------------------------
// Kernel 1: Xproj — persistent-B fp16 dot2 GEMM (proven ~370-450us). Unchanged.
// -------------------------------------------------------------------------
__global__ __launch_bounds__(256) void xproj_kernel(
    const float* __restrict__ input,
    const float* __restrict__ gate_w,
    const float* __restrict__ gate_b,
    float* __restrict__ xproj)
{
    __shared__ _Float16 Bs[64][264];
    __shared__ _Float16 As[64][264];

    const int jt = blockIdx.x;         // 0..7
    const int mg = blockIdx.y;         // 0..63
    const int tid = threadIdx.x;
    const int tx = tid & 15, ty = tid >> 4;
    const int j0 = jt * 64;

    #pragma unroll
    for (int l = 0; l < 16; ++l) {
        int e = tid + l * 256;
        int i = e >> 6, kq = e & 63;
        float4 v = *(const float4*)&gate_w[(size_t)(j0 + i) * FANG + HID + kq * 4];
        *(h2*)&Bs[i][kq * 4]     = h2{(_Float16)v.x, (_Float16)v.y};
        *(h2*)&Bs[i][kq * 4 + 2] = h2{(_Float16)v.z, (_Float16)v.w};
    }

    const float4 gb = *(const float4*)&gate_b[j0 + tx * 4];

    for (int mt = 0; mt < 32; ++mt) {
        const int m0 = (mg * 32 + mt) * 64;
        __syncthreads();
        #pragma unroll
        for (int l = 0; l < 16; ++l) {
            int e = tid + l * 256;
            int i = e >> 6, kq = e & 63;
            float4 v = *(const float4*)&input[(size_t)(m0 + i) * IN_SZ + kq * 4];
            *(h2*)&As[i][kq * 4]     = h2{(_Float16)v.x, (_Float16)v.y};
            *(h2*)&As[i][kq * 4 + 2] = h2{(_Float16)v.z, (_Float16)v.w};
        }
        __syncthreads();

        float acc[4][4] = {};
        #pragma unroll
        for (int q = 0; q < 32; ++q) {
            const int k = ((q + tx) & 31) * 8;
            float4 av[4], bv[4];
            #pragma unroll
            for (int i = 0; i < 4; ++i)  av[i] = *(const float4*)&As[ty * 4 + i][k];
            #pragma unroll
            for (int jj = 0; jj < 4; ++jj) bv[jj] = *(const float4*)&Bs[tx * 4 + jj][k];
            #pragma unroll
            for (int i = 0; i < 4; ++i) {
                h2 a0 = bch2(av[i].x), a1 = bch2(av[i].y);
                h2 a2 = bch2(av[i].z), a3 = bch2(av[i].w);
                #pragma unroll
                for (int jj = 0; jj < 4; ++jj) {
                    acc[i][jj] = dot2f(a0, bch2(bv[jj].x), acc[i][jj]);
                    acc[i][jj] = dot2f(a1, bch2(bv[jj].y), acc[i][jj]);
                    acc[i][jj] = dot2f(a2, bch2(bv[jj].z), acc[i][jj]);
                    acc[i][jj] = dot2f(a3, bch2(bv[jj].w), acc[i][jj]);
                }
            }
        }

        #pragma unroll
        for (int i = 0; i < 4; ++i) {
            float4 o = {acc[i][0] + gb.x, acc[i][1] + gb.y,
                        acc[i][2] + gb.z, acc[i][3] + gb.w};
            *(float4*)&xproj[(size_t)(m0 + ty * 4 + i) * HID + j0 + tx * 4] = o;
        }
    }
}

// -------------------------------------------------------------------------
// Kernel 2: ZERO-EXCHANGE recurrence. 64 WGs (one per batch row), 512 thr.
// Full W_h lives on one CU: 384 KB in VGPRs (192 regs/thread) + 128 KB in
// LDS (streamed each step at the 128 B/cy LDS floor ~ 1024 cy). h lives in
// a 2-KB double-buffered LDS array -- no global traffic, no polls, no tags,
// no cross-WG ordering assumptions of ANY kind.
// Thread (g = tid>>2, c = tid&3): rows g*4..g*4+3, k in [c*128, c*128+128).
//   VGPR weights: h2 slots s=0..47 (k = c*128 + 2s), w2[rr*48+s], 192 regs.
//   LDS  weights: s=48..63, lane-interleaved quads so each ds_read_b128 is
//   a full-bandwidth coalesced stream: word addr = wv*4096 + lane*4 + n*256.
// h LDS layout: word w (= j/2) at (w>>6)*68 + (w&63): 4 chunks, stride 68
//   -> the 4 per-wave broadcast reads hit disjoint bank quads.
// -------------------------------------------------------------------------
__global__ __launch_bounds__(512, 2) void lstm_kernel(
    const float* __restrict__ gate_w,
    const float* __restrict__ xproj,
    float* __restrict__ hfin)
{
    const int b    = blockIdx.x;     // batch row
    const int tid  = threadIdx.x;
    const int g    = tid >> 2;       // 0..127
    const int c    = tid & 3;        // 0..3
    const int j0   = g * 4;
    const int wv   = tid >> 6;       // wave 0..7
    const int lane = tid & 63;
    const int k0   = c * 128;

    __shared__ u32 wlds[32768];      // 128 KB LDS-resident weight slice
    __shared__ u32 hbuf[2][272];     // h double buffer (256 words + pads)

    // ---- one-time init ----
    h2 w2[192];                       // 4 rows x 48 h2 (96 k) in VGPRs
    #pragma unroll
    for (int rr = 0; rr < 4; ++rr) {
        const float* wr = gate_w + (size_t)(j0 + rr) * FANG + k0;
        #pragma unroll
        for (int f = 0; f < 24; ++f) {
            float4 v = *(const float4*)(wr + f * 4);
            w2[rr * 48 + f * 2]     = h2{(_Float16)v.x, (_Float16)v.y};
            w2[rr * 48 + f * 2 + 1] = h2{(_Float16)v.z, (_Float16)v.w};
        }
    }
    const int wbase = wv * 4096 + lane * 4;   // this thread's LDS-weight lane slot
    #pragma unroll
    for (int hq = 0; hq < 4; ++hq) {
        #pragma unroll
        for (int rr = 0; rr < 4; ++rr) {
            const float* wr = gate_w + (size_t)(j0 + rr) * FANG + k0 + 96 + hq * 8;
            float4 v0 = *(const float4*)(wr);
            float4 v1 = *(const float4*)(wr + 4);
            u32 q[4] = { packh2(v0.x, v0.y), packh2(v0.z, v0.w),
                         packh2(v1.x, v1.y), packh2(v1.z, v1.w) };
            *(uint4*)&wlds[wbase + (hq * 4 + rr) * 256] = *(const uint4*)q;
        }
    }
    if (tid < 272) hbuf[0][tid] = 0;   // h = 0 at step 0

    float cv[4] = {0.f, 0.f, 0.f, 0.f};   // cell state (owner lanes c==0)

    for (int st = 0; st < TOT_STEPS; ++st) {
        const int t   = st & (T_STEPS - 1);
        const int buf = st & 1;

        float4 xq = {0.f, 0.f, 0.f, 0.f};
        if (c == 0)
            xq = *(const float4*)&xproj[((size_t)t * BATCH + b) * HID + j0];

        __syncthreads();   // the only barrier per step

        const u32* hb = &hbuf[buf][c * 68];
        float a[4] = {0.f, 0.f, 0.f, 0.f};

        // VGPR-weight dot: 12 broadcast b128 h-reads x 16 dot2
        #pragma unroll
        for (int q = 0; q < 12; ++q) {
            float4 rv = *(const float4*)(hb + q * 4);
            h2 x0 = bch2(rv.x), x1 = bch2(rv.y), x2 = bch2(rv.z), x3 = bch2(rv.w);
            #pragma unroll
            for (int rr = 0; rr < 4; ++rr) {
                a[rr] = dot2f(w2[rr * 48 + q * 4 + 0], x0, a[rr]);
                a[rr] = dot2f(w2[rr * 48 + q * 4 + 1], x1, a[rr]);
                a[rr] = dot2f(w2[rr * 48 + q * 4 + 2], x2, a[rr]);
                a[rr] = dot2f(w2[rr * 48 + q * 4 + 3], x3, a[rr]);
            }
        }
        // LDS-weight dot: 16 streamed b128 weight reads x 4 dot2
        #pragma unroll
        for (int hq = 0; hq < 4; ++hq) {
            float4 rv = *(const float4*)(hb + 48 + hq * 4);
            h2 x0 = bch2(rv.x), x1 = bch2(rv.y), x2 = bch2(rv.z), x3 = bch2(rv.w);
            #pragma unroll
            for (int rr = 0; rr < 4; ++rr) {
                float4 wq = *(const float4*)&wlds[wbase + (hq * 4 + rr) * 256];
                a[rr] = dot2f(bch2(wq.x), x0, a[rr]);
                a[rr] = dot2f(bch2(wq.y), x1, a[rr]);
                a[rr] = dot2f(bch2(wq.z), x2, a[rr]);
                a[rr] = dot2f(bch2(wq.w), x3, a[rr]);
            }
        }

        // 4-lane quad reduce (pure VALU)
        #pragma unroll
        for (int rr = 0; rr < 4; ++rr) a[rr] = reduce4(a[rr]);

        if (c == 0) {
            float xs[4] = {xq.x, xq.y, xq.z, xq.w};
            float hf[4];
            #pragma unroll
            for (int rr = 0; rr < 4; ++rr) {
                float gg = a[rr] + xs[rr];
                gg = fminf(fmaxf(gg, -30.0f), 30.0f);
                float sg = 1.0f / (1.0f + __expf(-gg));     // sigmoid
                float e2 = __expf(2.0f * gg);               // tanh(g)
                float ch = (e2 - 1.0f) / (e2 + 1.0f);
                cv[rr] = cv[rr] * sg + ch * sg;
                float ca = fminf(fmaxf(cv[rr], -15.0f), 15.0f);
                float e3 = __expf(2.0f * ca);               // tanh(c)
                float th = (e3 - 1.0f) / (e3 + 1.0f);
                hf[rr] = th * sg;
            }
            const int w0 = g * 2;                           // word index of row pair
            u32* dst = &hbuf[buf ^ 1][(w0 >> 6) * 68 + (w0 & 63)];
            dst[0] = packh2(hf[0], hf[1]);
            dst[1] = packh2(hf[2], hf[3]);
            if (st == TOT_STEPS - 1) {
                float4 o = {hf[0], hf[1], hf[2], hf[3]};
                *(float4*)&hfin[(size_t)b * HID + j0] = o;
            }
        }
        // no trailing barrier: writes target hbuf[buf^1]; the next step's
        // top barrier orders them before its reads (single-barrier-safe:
        // any stale reader of hbuf[buf^1] finished before this barrier).
    }
}

// -------------------------------------------------------------------------
// Kernel 3: output = h_final @ out_w.T + out_b, h_final fp32 from hfin.
// -------------------------------------------------------------------------
__global__ __launch_bounds__(256) void out_kernel(
    const float* __restrict__ hfin,
    const float* __restrict__ out_w,
    const float* __restrict__ out_b,
    float* __restrict__ out)
{
    const int b  = blockIdx.x;    // 64
    const int jt = threadIdx.x;   // 256
    __shared__ float hrow[512];

    hrow[jt]       = hfin[(size_t)b * HID + jt];
    hrow[jt + 256] = hfin[(size_t)b * HID + 256 + jt];
    __syncthreads();

    float acc = out_b[jt];
    const float* wr = out_w + (size_t)jt * HID;
    #pragma unroll 8
    for (int k = 0; k < HID; ++k)
        acc += hrow[k] * wr[k];
    out[(size_t)b * IN_SZ + jt] = acc;
}

// -------------------------------------------------------------------------
extern "C" void kernel_launch(void* const* d_in, const int* in_sizes, int n_in,
                              void* d_out, int out_size, void* d_ws, size_t ws_size,
                              hipStream_t stream)
{
    const float* input  = (const float*)d_in[0];
    const float* gate_w = (const float*)d_in[1];
    const float* gate_b = (const float*)d_in[2];
    const float* out_w  = (const float*)d_in[3];
    const float* out_b  = (const float*)d_in[4];
    float* out = (float*)d_out;

    // ws layout: Xproj fp32 (256 MB) | hfin [64][512] fp32 (128 KB)
    float* xproj = (float*)d_ws;
    const size_t xbytes = (size_t)T_STEPS * BATCH * HID * sizeof(float);
    float* hfin = (float*)((char*)d_ws + xbytes);

    // no memset needed: zero cross-launch state (h_lds zeroed in-kernel,
    // hfin fully overwritten before out_kernel reads it).

    dim3 g1(8, 64);
    xproj_kernel<<<g1, 256, 0, stream>>>(input, gate_w, gate_b, xproj);
    lstm_kernel<<<BATCH, 512, 0, stream>>>(gate_w, xproj, hfin);
    out_kernel<<<64, 256, 0, stream>>>(hfin, out_w, out_b, out);
}

// Round 8
// 6475.352 us; speedup vs baseline: 1.3984x; 1.3984x over previous
//
#include <hip/hip_runtime.h>
#include <stdint.h>

#define T_STEPS 2048
#define BATCH   64
#define IN_SZ   256
#define HID     512
#define FANG    768          // HID + IN_SZ
#define NLAYER  2
#define TOT_STEPS (T_STEPS*NLAYER)

typedef _Float16 h2 __attribute__((ext_vector_type(2)));
typedef unsigned long long u64;
typedef unsigned int u32;

__device__ __forceinline__ float dot2f(h2 a, h2 b, float c) {
#if __has_builtin(__builtin_amdgcn_fdot2)
    return __builtin_amdgcn_fdot2(a, b, c, false);
#else
    return c + (float)a.x * (float)b.x + (float)a.y * (float)b.y;
#endif
}

__device__ __forceinline__ u32 packh2(float a, float b) {
    h2 t{(_Float16)a, (_Float16)b};
    return __builtin_bit_cast(u32, t);
}
__device__ __forceinline__ h2 bch2(float v) { return __builtin_bit_cast(h2, v); }
__device__ __forceinline__ h2 bch2u(u32 v)  { return __builtin_bit_cast(h2, v); }

// Round-2/6-PROVEN exchange: relaxed agent-scope atomics on one u64
// (tag32 | 2xfp16). Tag and data in ONE word -> no fences needed.
__device__ __forceinline__ u64 ld_llc(const u64* p) {
    return __hip_atomic_load(p, __ATOMIC_RELAXED, __HIP_MEMORY_SCOPE_AGENT);
}
__device__ __forceinline__ void st_llc(u64* p, u64 v) {
    __hip_atomic_store(p, v, __ATOMIC_RELAXED, __HIP_MEMORY_SCOPE_AGENT);
}

// DPP quad reduce (proven round 6): xor1 + xor2 -> every lane has quad sum.
template<int CTRL>
__device__ __forceinline__ float dpp_add(float x) {
    int xi = __builtin_bit_cast(int, x);
    int yi = __builtin_amdgcn_update_dpp(0, xi, CTRL, 0xf, 0xf, true);
    return x + __builtin_bit_cast(float, yi);
}
__device__ __forceinline__ float reduce4(float x) {
    x = dpp_add<0xB1>(x);
    x = dpp_add<0x4E>(x);
    return x;
}

// -------------------------------------------------------------------------
// Kernel 1: Xproj — persistent-B fp16 dot2 GEMM (proven). Output now packed
// fp16 (u32 = 2 cols): halves store traffic here and fetch traffic in lstm.
// -------------------------------------------------------------------------
__global__ __launch_bounds__(256) void xproj_kernel(
    const float* __restrict__ input,
    const float* __restrict__ gate_w,
    const float* __restrict__ gate_b,
    u32* __restrict__ xp16)
{
    __shared__ _Float16 Bs[64][264];
    __shared__ _Float16 As[64][264];

    const int jt = blockIdx.x;         // 0..7
    const int mg = blockIdx.y;         // 0..63
    const int tid = threadIdx.x;
    const int tx = tid & 15, ty = tid >> 4;
    const int j0 = jt * 64;

    #pragma unroll
    for (int l = 0; l < 16; ++l) {
        int e = tid + l * 256;
        int i = e >> 6, kq = e & 63;
        float4 v = *(const float4*)&gate_w[(size_t)(j0 + i) * FANG + HID + kq * 4];
        *(h2*)&Bs[i][kq * 4]     = h2{(_Float16)v.x, (_Float16)v.y};
        *(h2*)&Bs[i][kq * 4 + 2] = h2{(_Float16)v.z, (_Float16)v.w};
    }

    const float4 gb = *(const float4*)&gate_b[j0 + tx * 4];

    for (int mt = 0; mt < 32; ++mt) {
        const int m0 = (mg * 32 + mt) * 64;
        __syncthreads();
        #pragma unroll
        for (int l = 0; l < 16; ++l) {
            int e = tid + l * 256;
            int i = e >> 6, kq = e & 63;
            float4 v = *(const float4*)&input[(size_t)(m0 + i) * IN_SZ + kq * 4];
            *(h2*)&As[i][kq * 4]     = h2{(_Float16)v.x, (_Float16)v.y};
            *(h2*)&As[i][kq * 4 + 2] = h2{(_Float16)v.z, (_Float16)v.w};
        }
        __syncthreads();

        float acc[4][4] = {};
        #pragma unroll
        for (int q = 0; q < 32; ++q) {
            const int k = ((q + tx) & 31) * 8;
            float4 av[4], bv[4];
            #pragma unroll
            for (int i = 0; i < 4; ++i)  av[i] = *(const float4*)&As[ty * 4 + i][k];
            #pragma unroll
            for (int jj = 0; jj < 4; ++jj) bv[jj] = *(const float4*)&Bs[tx * 4 + jj][k];
            #pragma unroll
            for (int i = 0; i < 4; ++i) {
                h2 a0 = bch2(av[i].x), a1 = bch2(av[i].y);
                h2 a2 = bch2(av[i].z), a3 = bch2(av[i].w);
                #pragma unroll
                for (int jj = 0; jj < 4; ++jj) {
                    acc[i][jj] = dot2f(a0, bch2(bv[jj].x), acc[i][jj]);
                    acc[i][jj] = dot2f(a1, bch2(bv[jj].y), acc[i][jj]);
                    acc[i][jj] = dot2f(a2, bch2(bv[jj].z), acc[i][jj]);
                    acc[i][jj] = dot2f(a3, bch2(bv[jj].w), acc[i][jj]);
                }
            }
        }

        #pragma unroll
        for (int i = 0; i < 4; ++i) {
            uint2 ww = { packh2(acc[i][0] + gb.x, acc[i][1] + gb.y),
                         packh2(acc[i][2] + gb.z, acc[i][3] + gb.w) };
            *(uint2*)&xp16[(size_t)(m0 + ty * 4 + i) * 256 + ((j0 + tx * 4) >> 1)] = ww;
        }
    }
}

// -------------------------------------------------------------------------
// Kernel 2: recurrence. 128 WGs = 2 slices x 64 batch, 512 threads.
// Slice s owns rows [s*256, s*256+256). Thread (g = tid>>2, c = tid&3):
// row pair j0 = s*256 + g*2, k-cols = own-slice [s*256 + c*64, +64) plus
// remote-slice [(1-s)*256 + c*64, +64)  => 128 h2 weights, ALL in VGPRs.
// Per step: probe remote -> bar1 -> own-half dot (hides the LLC RT) ->
// stage remote -> bar2 -> remote-half dot -> quad reduce -> act (c==0 owns
// a row PAIR: packs its own exchange word, no shuffles).
// h exchange: hx[2][64][256] u64 (tag|2xfp16), single remote producer.
// LDS h words: chunk layout (w>>6)*68 + (w&63) -> conflict-free reads.
// -------------------------------------------------------------------------
__global__ __launch_bounds__(512, 2) void lstm_kernel(
    const float* __restrict__ gate_w,
    const u32* __restrict__ xp16,
    u64* __restrict__ hx)
{
    const int blk = blockIdx.x;     // 0..127
    const int s   = blk >> 6;       // slice 0..1
    const int b   = blk & 63;       // batch row
    const int tid = threadIdx.x;    // 0..511
    const int g   = tid >> 2;       // row-pair 0..127
    const int c   = tid & 3;        // k-quarter
    const int j0  = s * 256 + g * 2;

    __shared__ u32 hbuf[2][280];    // 4 chunks x 68-word stride

    // weights: w2[p*64 + q*8 + wq*2 + r], p=0 own-slice cols, p=1 remote
    h2 w2[128];
    #pragma unroll
    for (int p = 0; p < 2; ++p) {
        const int kb = (p == 0 ? s : 1 - s) * 256 + c * 64;
        #pragma unroll
        for (int r = 0; r < 2; ++r) {
            const float* wr = gate_w + (size_t)(j0 + r) * FANG + kb;
            #pragma unroll
            for (int f = 0; f < 16; ++f) {
                float4 v = *(const float4*)(wr + f * 4);
                const int w0 = 2 * f, w1 = 2 * f + 1;
                w2[p * 64 + (w0 >> 2) * 8 + (w0 & 3) * 2 + r] = h2{(_Float16)v.x, (_Float16)v.y};
                w2[p * 64 + (w1 >> 2) * 8 + (w1 & 3) * 2 + r] = h2{(_Float16)v.z, (_Float16)v.w};
            }
        }
    }

    // LDS base offsets for this thread's own/remote 32-word sub-chunks
    const int cb_own = (2 * s       + (c >> 1)) * 68 + (c & 1) * 32;
    const int cb_rem = (2 * (1 - s) + (c >> 1)) * 68 + (c & 1) * 32;
    // poller: thread i<128 handles remote word (1-s)*128 + i
    const int prw   = (1 - s) * 128 + tid;
    const int plds  = (2 * (1 - s) + (tid >> 6)) * 68 + (tid & 63);
    // bypass (producer) word: s*128 + g
    const int blds  = (2 * s + (g >> 6)) * 68 + (g & 63);

    if (tid < 280) { hbuf[0][tid] = 0; }   // h = 0 for step 0

    float cv0 = 0.f, cv1 = 0.f;            // cell state (c==0 lanes, row pair)

    for (int st = 0; st < TOT_STEPS; ++st) {
        const int t   = st & (T_STEPS - 1);
        const int buf = st & 1;

        // xproj word for this act-lane's row pair (overlaps everything)
        u32 xw = 0;
        if (c == 0) xw = xp16[((size_t)t * BATCH + b) * 256 + s * 128 + g];

        // first probe of the remote word, in flight during own-half dot
        const u64* pp = hx + ((size_t)buf * BATCH + b) * 256 + prw;
        u64 pv = 0;
        if (tid < 128) pv = ld_llc(pp);

        __syncthreads();   // bar1: publishes last step's bypass (own-slice h)

        // ---- own-half dot (local data, hides the LLC round trip) ----
        float a0 = 0.f, a1 = 0.f;
        {
            const u32* hb = &hbuf[buf][cb_own];
            #pragma unroll
            for (int q = 0; q < 8; ++q) {
                float4 rv = *(const float4*)(hb + q * 4);
                h2 x0 = bch2(rv.x), x1 = bch2(rv.y), x2 = bch2(rv.z), x3 = bch2(rv.w);
                a0 = dot2f(w2[q*8+0], x0, a0); a1 = dot2f(w2[q*8+1], x0, a1);
                a0 = dot2f(w2[q*8+2], x1, a0); a1 = dot2f(w2[q*8+3], x1, a1);
                a0 = dot2f(w2[q*8+4], x2, a0); a1 = dot2f(w2[q*8+5], x2, a1);
                a0 = dot2f(w2[q*8+6], x3, a0); a1 = dot2f(w2[q*8+7], x3, a1);
            }
        }

        // ---- detect + stage the remote slice (single producer) ----
        if (tid < 128) {
            u64 v = pv;
            int spin = 0;
            while ((u32)(v >> 32) != (u32)st) {
                v = ld_llc(pp);
                if (++spin > (1 << 16)) break;        // safety bailout
                if (spin > 64) __builtin_amdgcn_s_sleep(1);
            }
            hbuf[buf][plds] = (u32)v;
        }
        __syncthreads();   // bar2: remote h staged

        // ---- remote-half dot ----
        {
            const u32* hb = &hbuf[buf][cb_rem];
            #pragma unroll
            for (int q = 0; q < 8; ++q) {
                float4 rv = *(const float4*)(hb + q * 4);
                h2 x0 = bch2(rv.x), x1 = bch2(rv.y), x2 = bch2(rv.z), x3 = bch2(rv.w);
                a0 = dot2f(w2[64+q*8+0], x0, a0); a1 = dot2f(w2[64+q*8+1], x0, a1);
                a0 = dot2f(w2[64+q*8+2], x1, a0); a1 = dot2f(w2[64+q*8+3], x1, a1);
                a0 = dot2f(w2[64+q*8+4], x2, a0); a1 = dot2f(w2[64+q*8+5], x2, a1);
                a0 = dot2f(w2[64+q*8+6], x3, a0); a1 = dot2f(w2[64+q*8+7], x3, a1);
            }
        }

        // quad reduce across the 4 k-lanes
        a0 = reduce4(a0);
        a1 = reduce4(a1);

        if (c == 0) {
            h2 xp = bch2u(xw);
            float hf0, hf1;
            {
                float gg = a0 + (float)xp.x;
                gg = fminf(fmaxf(gg, -30.0f), 30.0f);
                float sg = 1.0f / (1.0f + __expf(-gg));
                float e2 = __expf(2.0f * gg);
                float ch = (e2 - 1.0f) / (e2 + 1.0f);
                cv0 = cv0 * sg + ch * sg;
                float ca = fminf(fmaxf(cv0, -15.0f), 15.0f);
                float e3 = __expf(2.0f * ca);
                hf0 = ((e3 - 1.0f) / (e3 + 1.0f)) * sg;
            }
            {
                float gg = a1 + (float)xp.y;
                gg = fminf(fmaxf(gg, -30.0f), 30.0f);
                float sg = 1.0f / (1.0f + __expf(-gg));
                float e2 = __expf(2.0f * gg);
                float ch = (e2 - 1.0f) / (e2 + 1.0f);
                cv1 = cv1 * sg + ch * sg;
                float ca = fminf(fmaxf(cv1, -15.0f), 15.0f);
                float e3 = __expf(2.0f * ca);
                hf1 = ((e3 - 1.0f) / (e3 + 1.0f)) * sg;
            }
            u32 pk = packh2(hf0, hf1);
            // publish to the remote WG (tagged word) + local bypass to LDS
            st_llc(hx + ((size_t)((st + 1) & 1) * BATCH + b) * 256 + s * 128 + g,
                   (u64)pk | ((u64)(u32)(st + 1) << 32));
            hbuf[buf ^ 1][blds] = pk;
        }
        // no trailing barrier: bypass writes hbuf[buf^1]; bar1 of the next
        // step orders them before any read. Pollers of step st+1 write
        // remote words of hbuf[buf^1] (disjoint from bypass's own words).
    }
}

// -------------------------------------------------------------------------
// Kernel 3: output = h_final @ out_w.T + out_b. Final h in hx buffer 0
// (TOT_STEPS even), 2 fp16 per word's low 32 bits. Same as proven round 6.
// -------------------------------------------------------------------------
__global__ __launch_bounds__(256) void out_kernel(
    const u64* __restrict__ hx,
    const float* __restrict__ out_w,
    const float* __restrict__ out_b,
    float* __restrict__ out)
{
    const int b  = blockIdx.x;    // 64
    const int jt = threadIdx.x;   // 256
    __shared__ float hrow[512];

    {
        u64 v = hx[(size_t)b * 256 + jt];
        h2 pr = bch2u((u32)v);
        hrow[2 * jt]     = (float)pr.x;
        hrow[2 * jt + 1] = (float)pr.y;
    }
    __syncthreads();

    float acc = out_b[jt];
    const float* wr = out_w + (size_t)jt * HID;
    #pragma unroll 8
    for (int k = 0; k < HID; ++k)
        acc += hrow[k] * wr[k];
    out[(size_t)b * IN_SZ + jt] = acc;
}

// -------------------------------------------------------------------------
extern "C" void kernel_launch(void* const* d_in, const int* in_sizes, int n_in,
                              void* d_out, int out_size, void* d_ws, size_t ws_size,
                              hipStream_t stream)
{
    const float* input  = (const float*)d_in[0];
    const float* gate_w = (const float*)d_in[1];
    const float* gate_b = (const float*)d_in[2];
    const float* out_w  = (const float*)d_in[3];
    const float* out_b  = (const float*)d_in[4];
    float* out = (float*)d_out;

    // ws layout: Xproj fp16-packed (128 MB) | hx [2][64][256] u64 (256 KB)
    u32* xp16 = (u32*)d_ws;
    const size_t xbytes = (size_t)T_STEPS * BATCH * 256 * sizeof(u32);
    u64* hx = (u64*)((char*)d_ws + xbytes);

    // zero the exchange every launch: tag 0 == initial h = 0; graph replays
    // must never see stale tags.
    (void)hipMemsetAsync(hx, 0, (size_t)2 * BATCH * 256 * sizeof(u64), stream);

    dim3 g1(8, 64);
    xproj_kernel<<<g1, 256, 0, stream>>>(input, gate_w, gate_b, xp16);
    lstm_kernel<<<128, 512, 0, stream>>>(gate_w, xp16, hx);
    out_kernel<<<64, 256, 0, stream>>>(hx, out_w, out_b, out);
}